// Round 1
// baseline (66.793 us; speedup 1.0000x reference)
//
#include <hip/hip_runtime.h>
#include <math.h>

#define BATCH 32
#define NSAMP 262144
#define NKNOT 256
#define CHUNK 128
#define NC (NSAMP / CHUNK)          // 2048 chunks per row
#define TC (BATCH * NC)             // 65536 total chunks
#define EPSV 0.001f

__device__ __forceinline__ float fast_tanh(float x) {
    // tanh(x) = 1 - 2/(exp(2x)+1); branch-free, ~1e-7 abs error
    float e = __expf(2.0f * x);
    float r = __builtin_amdgcn_rcpf(e + 1.0f);
    return fmaf(-2.0f, r, 1.0f);
}

// ---------------- Kernel A: per-chunk affine maps (T, p) ----------------
__global__ __launch_bounds__(256) void k_build(
    const float* __restrict__ x,
    const float* __restrict__ cl,    // [BATCH][NKNOT][5]
    float* __restrict__ rec)         // 6 arrays of TC floats: m00,m01,m10,m11,p0,p1
{
    int chunk = blockIdx.x * blockDim.x + threadIdx.x;
    int r = chunk >> 11;             // / NC
    int c = chunk & (NC - 1);
    const float scale = 255.0f / 262143.0f;
    int t0 = c * CHUNK;
    float pos0 = (float)t0 * scale;
    float fiA = floorf(pos0);
    int idxA = (int)fiA;
    const float* kb = cl + (size_t)r * NKNOT * 5;
    int i0 = idxA;
    int i1 = min(idxA + 1, NKNOT - 1);
    int i2 = min(idxA + 2, NKNOT - 1);
    // channels 0,1 at the (up to) 3 knots this chunk can touch
    float k00 = kb[i0 * 5 + 0], k01 = kb[i1 * 5 + 0], k02 = kb[i2 * 5 + 0];
    float k10 = kb[i0 * 5 + 1], k11 = kb[i1 * 5 + 1], k12 = kb[i2 * 5 + 1];

    const float* xp = x + (size_t)r * NSAMP + t0;
    float p1 = 0.f, p2 = 0.f;        // particular (zero init)
    float A1 = 1.f, A2 = 0.f;        // homogeneous resp to (1,0)
    float B1 = 0.f, B2 = 1.f;        // homogeneous resp to (0,1)
    const float stab = 1.0f - EPSV;
    const float stab2 = 2.0f * stab;

    for (int j = 0; j < CHUNK; j += 4) {
        float4 xv = *(const float4*)(xp + j);
        #pragma unroll
        for (int q = 0; q < 4; ++q) {
            float xs = (&xv.x)[q];
            float wA = fmaf((float)(j + q), scale, pos0) - fiA;
            bool sel = wA >= 1.0f;
            float w = sel ? (wA - 1.0f) : wA;
            float l0a = sel ? k01 : k00, l0b = sel ? k02 : k01;
            float l1a = sel ? k11 : k10, l1b = sel ? k12 : k11;
            float l0 = fmaf(w, l0b - l0a, l0a);
            float l1 = fmaf(w, l1b - l1a, l1a);
            float a1 = stab2 * fast_tanh(l0);
            float a1a = fabsf(a1);
            float a2 = 0.5f * fmaf((2.0f - a1a) * stab, fast_tanh(l1), a1a);
            float p  = fmaf(-a2, p2, xs);  p  = fmaf(-a1, p1, p);
            float hA = fmaf(-a1, A1, -a2 * A2);
            float hB = fmaf(-a1, B1, -a2 * B2);
            p2 = p1; p1 = p;
            A2 = A1; A1 = hA;
            B2 = B1; B1 = hB;
        }
    }
    // s_end = T * s_start + p ; columns of T are the homogeneous responses
    rec[0 * TC + chunk] = A1;  // m00
    rec[1 * TC + chunk] = B1;  // m01
    rec[2 * TC + chunk] = A2;  // m10
    rec[3 * TC + chunk] = B2;  // m11
    rec[4 * TC + chunk] = p1;  // p0
    rec[5 * TC + chunk] = p2;  // p1
}

// ---------------- Kernel B: per-row affine prefix scan over chunks ----------------
__device__ __forceinline__ int swz(int i) { return i + (i >> 5); }  // kill stride-32 bank conflicts

__global__ __launch_bounds__(64) void k_scan(
    const float* __restrict__ rec,
    float* __restrict__ init)        // 2 arrays of TC floats: y[t0-1], y[t0-2]
{
    __shared__ float sm[6][NC + (NC >> 5)];
    int r = blockIdx.x;
    int lane = threadIdx.x;
    const int RPL = NC / 64;         // 32 records per lane

    for (int a = 0; a < 6; ++a)
        for (int i = lane; i < NC; i += 64)
            sm[a][swz(i)] = rec[a * TC + r * NC + i];
    __syncthreads();

    int lbase = lane * RPL;
    // local sequential compose of this lane's records (later ∘ earlier)
    float L00 = 1.f, L01 = 0.f, L10 = 0.f, L11 = 1.f, Lv0 = 0.f, Lv1 = 0.f;
    for (int j = 0; j < RPL; ++j) {
        int s = swz(lbase + j);
        float r00 = sm[0][s], r01 = sm[1][s], r10 = sm[2][s], r11 = sm[3][s];
        float q0 = sm[4][s], q1 = sm[5][s];
        float n00 = r00 * L00 + r01 * L10;
        float n01 = r00 * L01 + r01 * L11;
        float n10 = r10 * L00 + r11 * L10;
        float n11 = r10 * L01 + r11 * L11;
        float nv0 = fmaf(r00, Lv0, fmaf(r01, Lv1, q0));
        float nv1 = fmaf(r10, Lv0, fmaf(r11, Lv1, q1));
        L00 = n00; L01 = n01; L10 = n10; L11 = n11; Lv0 = nv0; Lv1 = nv1;
    }
    // inclusive wave scan (compose with earlier = lower lanes)
    for (int d = 1; d < 64; d <<= 1) {
        float o00 = __shfl_up(L00, d), o01 = __shfl_up(L01, d);
        float o10 = __shfl_up(L10, d), o11 = __shfl_up(L11, d);
        float ov0 = __shfl_up(Lv0, d), ov1 = __shfl_up(Lv1, d);
        if (lane >= d) {
            float n00 = L00 * o00 + L01 * o10;
            float n01 = L00 * o01 + L01 * o11;
            float n10 = L10 * o00 + L11 * o10;
            float n11 = L10 * o01 + L11 * o11;
            float nv0 = fmaf(L00, ov0, fmaf(L01, ov1, Lv0));
            float nv1 = fmaf(L10, ov0, fmaf(L11, ov1, Lv1));
            L00 = n00; L01 = n01; L10 = n10; L11 = n11; Lv0 = nv0; Lv1 = nv1;
        }
    }
    // exclusive: state at this lane's first chunk (applied to zero init -> just v)
    float ev0 = __shfl_up(Lv0, 1);
    float ev1 = __shfl_up(Lv1, 1);
    float s0 = (lane == 0) ? 0.f : ev0;
    float s1 = (lane == 0) ? 0.f : ev1;
    // replay: write each chunk's initial state, advance through own records
    for (int j = 0; j < RPL; ++j) {
        int cidx = r * NC + lbase + j;
        int s = swz(lbase + j);
        init[cidx] = s0;
        init[TC + cidx] = s1;
        float r00 = sm[0][s], r01 = sm[1][s], r10 = sm[2][s], r11 = sm[3][s];
        float q0 = sm[4][s], q1 = sm[5][s];
        float ns0 = fmaf(r00, s0, fmaf(r01, s1, q0));
        float ns1 = fmaf(r10, s0, fmaf(r11, s1, q1));
        s0 = ns0; s1 = ns1;
    }
}

// ---------------- Kernel C: rerun chunks with correct init, fused FIR ----------------
__global__ __launch_bounds__(256) void k_apply(
    const float* __restrict__ x,
    const float* __restrict__ cl,
    const float* __restrict__ init,
    float* __restrict__ out)
{
    int chunk = blockIdx.x * blockDim.x + threadIdx.x;
    int r = chunk >> 11;
    int c = chunk & (NC - 1);
    const float scale = 255.0f / 262143.0f;
    int t0 = c * CHUNK;
    float pos0 = (float)t0 * scale;
    float fiA = floorf(pos0);
    int idxA = (int)fiA;
    const float* kb = cl + (size_t)r * NKNOT * 5;
    int i0 = idxA;
    int i1 = min(idxA + 1, NKNOT - 1);
    int i2 = min(idxA + 2, NKNOT - 1);
    float k00 = kb[i0 * 5 + 0], k01 = kb[i1 * 5 + 0], k02 = kb[i2 * 5 + 0];
    float k10 = kb[i0 * 5 + 1], k11 = kb[i1 * 5 + 1], k12 = kb[i2 * 5 + 1];
    float k20 = kb[i0 * 5 + 2], k21 = kb[i1 * 5 + 2], k22 = kb[i2 * 5 + 2];
    float k30 = kb[i0 * 5 + 3], k31 = kb[i1 * 5 + 3], k32 = kb[i2 * 5 + 3];
    float k40 = kb[i0 * 5 + 4], k41 = kb[i1 * 5 + 4], k42 = kb[i2 * 5 + 4];

    const float* xp = x + (size_t)r * NSAMP + t0;
    float* op = out + (size_t)r * NSAMP + t0;
    float y1 = init[chunk];
    float y2 = init[TC + chunk];
    const float stab = 1.0f - EPSV;
    const float stab2 = 2.0f * stab;

    for (int j = 0; j < CHUNK; j += 4) {
        float4 xv = *(const float4*)(xp + j);
        float4 ov;
        #pragma unroll
        for (int q = 0; q < 4; ++q) {
            float xs = (&xv.x)[q];
            float wA = fmaf((float)(j + q), scale, pos0) - fiA;
            bool sel = wA >= 1.0f;
            float w = sel ? (wA - 1.0f) : wA;
            float l0a = sel ? k01 : k00, l0b = sel ? k02 : k01;
            float l1a = sel ? k11 : k10, l1b = sel ? k12 : k11;
            float b0a = sel ? k21 : k20, b0b = sel ? k22 : k21;
            float b1a = sel ? k31 : k30, b1b = sel ? k32 : k31;
            float b2a = sel ? k41 : k40, b2b = sel ? k42 : k41;
            float l0 = fmaf(w, l0b - l0a, l0a);
            float l1 = fmaf(w, l1b - l1a, l1a);
            float b0 = fmaf(w, b0b - b0a, b0a);
            float b1 = fmaf(w, b1b - b1a, b1a);
            float b2 = fmaf(w, b2b - b2a, b2a);
            float a1 = stab2 * fast_tanh(l0);
            float a1a = fabsf(a1);
            float a2 = 0.5f * fmaf((2.0f - a1a) * stab, fast_tanh(l1), a1a);
            float y = fmaf(-a2, y2, xs);  y = fmaf(-a1, y1, y);
            (&ov.x)[q] = fmaf(b0, y, fmaf(b1, y1, b2 * y2));
            y2 = y1; y1 = y;
        }
        *(float4*)(op + j) = ov;
    }
}

extern "C" void kernel_launch(void* const* d_in, const int* in_sizes, int n_in,
                              void* d_out, int out_size, void* d_ws, size_t ws_size,
                              hipStream_t stream) {
    const float* x  = (const float*)d_in[0];   // [32][262144]
    const float* cl = (const float*)d_in[1];   // [32][256][5]
    float* out = (float*)d_out;
    float* rec  = (float*)d_ws;                // 6*TC floats
    float* init = rec + 6 * TC;                // 2*TC floats  (total 2 MiB)

    hipLaunchKernelGGL(k_build, dim3(TC / 256), dim3(256), 0, stream, x, cl, rec);
    hipLaunchKernelGGL(k_scan,  dim3(BATCH),    dim3(64),  0, stream, rec, init);
    hipLaunchKernelGGL(k_apply, dim3(TC / 256), dim3(256), 0, stream, x, cl, init, out);
}

// Round 2
// 55.543 us; speedup vs baseline: 1.2025x; 1.2025x over previous
//
#include <hip/hip_runtime.h>
#include <math.h>

#define BATCH 32
#define NSAMP 262144
#define NKNOT 256
#define EPSV 0.001f
#define TSZ 16                       // samples per LDS write tile

__device__ __forceinline__ float fast_tanh(float x) {
    // tanh(x) = 1 - 2/(exp(2x)+1); branch-free, ~1e-7 abs error
    float e = __expf(2.0f * x);
    float r = __builtin_amdgcn_rcpf(e + 1.0f);
    return fmaf(-2.0f, r, 1.0f);
}

constexpr int ilog2c(int v) { int l = 0; while (v > 1) { v >>= 1; ++l; } return l; }

// ---------------- Kernel A: per-chunk affine maps (T, p) ----------------
template<int CH>
__global__ __launch_bounds__(256) void k_build(
    const float* __restrict__ x,
    const float* __restrict__ cl,    // [BATCH][NKNOT][5]
    float* __restrict__ rec)         // 6 arrays of TCv floats
{
    constexpr int NCv = NSAMP / CH;
    constexpr int TCv = BATCH * NCv;
    constexpr int LNC = ilog2c(NCv);
    int chunk = blockIdx.x * 256 + threadIdx.x;
    int r = chunk >> LNC;
    int c = chunk & (NCv - 1);
    const float scale = 255.0f / 262143.0f;
    int t0 = c * CH;
    float pos0 = (float)t0 * scale;
    float fiA = floorf(pos0);
    int idxA = (int)fiA;
    const float* kb = cl + (size_t)r * NKNOT * 5;
    int i0 = idxA;
    int i1 = min(idxA + 1, NKNOT - 1);
    int i2 = min(idxA + 2, NKNOT - 1);
    float k00 = kb[i0 * 5 + 0], k01 = kb[i1 * 5 + 0], k02 = kb[i2 * 5 + 0];
    float k10 = kb[i0 * 5 + 1], k11 = kb[i1 * 5 + 1], k12 = kb[i2 * 5 + 1];

    const float* xp = x + (size_t)chunk * CH;
    float p1 = 0.f, p2 = 0.f;        // particular (zero init)
    float A1 = 1.f, A2 = 0.f;        // homogeneous resp to (1,0)
    float B1 = 0.f, B2 = 1.f;        // homogeneous resp to (0,1)
    const float stab = 1.0f - EPSV;
    const float stab2 = 2.0f * stab;

    for (int j = 0; j < CH; j += 4) {
        float4 xv = *(const float4*)(xp + j);
        #pragma unroll
        for (int q = 0; q < 4; ++q) {
            float xs = (&xv.x)[q];
            float wA = fmaf((float)(j + q), scale, pos0) - fiA;
            bool sel = wA >= 1.0f;
            float w = sel ? (wA - 1.0f) : wA;
            float l0a = sel ? k01 : k00, l0b = sel ? k02 : k01;
            float l1a = sel ? k11 : k10, l1b = sel ? k12 : k11;
            float l0 = fmaf(w, l0b - l0a, l0a);
            float l1 = fmaf(w, l1b - l1a, l1a);
            float a1 = stab2 * fast_tanh(l0);
            float a1a = fabsf(a1);
            float a2 = 0.5f * fmaf((2.0f - a1a) * stab, fast_tanh(l1), a1a);
            float p  = fmaf(-a2, p2, xs);  p  = fmaf(-a1, p1, p);
            float hA = fmaf(-a1, A1, -a2 * A2);
            float hB = fmaf(-a1, B1, -a2 * B2);
            p2 = p1; p1 = p;
            A2 = A1; A1 = hA;
            B2 = B1; B1 = hB;
        }
    }
    rec[0 * TCv + chunk] = A1;  // m00
    rec[1 * TCv + chunk] = B1;  // m01
    rec[2 * TCv + chunk] = A2;  // m10
    rec[3 * TCv + chunk] = B2;  // m11
    rec[4 * TCv + chunk] = p1;  // p0
    rec[5 * TCv + chunk] = p2;  // p1
}

// ------- Kernel B: per-row hierarchical affine prefix scan (256 thr/row) -------
template<int CH>
__global__ __launch_bounds__(256) void k_scan(
    const float* __restrict__ rec,
    float* __restrict__ init)        // 2 arrays of TCv floats: y[t0-1], y[t0-2]
{
    constexpr int NCv = NSAMP / CH;
    constexpr int TCv = BATCH * NCv;
    constexpr int RPL = NCv / 256;   // records per thread
    __shared__ float wag[4][6];
    int r = blockIdx.x;
    int tid = threadIdx.x;
    int lane = tid & 63, wid = tid >> 6;
    int base = r * NCv + tid * RPL;

    // local sequential compose (later ∘ earlier)
    float L00 = 1.f, L01 = 0.f, L10 = 0.f, L11 = 1.f, Lv0 = 0.f, Lv1 = 0.f;
    for (int j = 0; j < RPL; ++j) {
        int idx = base + j;
        float r00 = rec[0 * TCv + idx], r01 = rec[1 * TCv + idx];
        float r10 = rec[2 * TCv + idx], r11 = rec[3 * TCv + idx];
        float q0  = rec[4 * TCv + idx], q1  = rec[5 * TCv + idx];
        float n00 = r00 * L00 + r01 * L10;
        float n01 = r00 * L01 + r01 * L11;
        float n10 = r10 * L00 + r11 * L10;
        float n11 = r10 * L01 + r11 * L11;
        float nv0 = fmaf(r00, Lv0, fmaf(r01, Lv1, q0));
        float nv1 = fmaf(r10, Lv0, fmaf(r11, Lv1, q1));
        L00 = n00; L01 = n01; L10 = n10; L11 = n11; Lv0 = nv0; Lv1 = nv1;
    }
    // inclusive wave scan
    for (int d = 1; d < 64; d <<= 1) {
        float o00 = __shfl_up(L00, d), o01 = __shfl_up(L01, d);
        float o10 = __shfl_up(L10, d), o11 = __shfl_up(L11, d);
        float ov0 = __shfl_up(Lv0, d), ov1 = __shfl_up(Lv1, d);
        if (lane >= d) {
            float n00 = L00 * o00 + L01 * o10;
            float n01 = L00 * o01 + L01 * o11;
            float n10 = L10 * o00 + L11 * o10;
            float n11 = L10 * o01 + L11 * o11;
            float nv0 = fmaf(L00, ov0, fmaf(L01, ov1, Lv0));
            float nv1 = fmaf(L10, ov0, fmaf(L11, ov1, Lv1));
            L00 = n00; L01 = n01; L10 = n10; L11 = n11; Lv0 = nv0; Lv1 = nv1;
        }
    }
    if (lane == 63) {
        wag[wid][0] = L00; wag[wid][1] = L01; wag[wid][2] = L10;
        wag[wid][3] = L11; wag[wid][4] = Lv0; wag[wid][5] = Lv1;
    }
    __syncthreads();
    // cross-wave prefix P = A_{wid-1} ∘ ... ∘ A_0
    float P00 = 1.f, P01 = 0.f, P10 = 0.f, P11 = 1.f, Pv0 = 0.f, Pv1 = 0.f;
    for (int w = 0; w < wid; ++w) {
        float a00 = wag[w][0], a01 = wag[w][1], a10 = wag[w][2];
        float a11 = wag[w][3], av0 = wag[w][4], av1 = wag[w][5];
        float n00 = a00 * P00 + a01 * P10;
        float n01 = a00 * P01 + a01 * P11;
        float n10 = a10 * P00 + a11 * P10;
        float n11 = a10 * P01 + a11 * P11;
        float nv0 = fmaf(a00, Pv0, fmaf(a01, Pv1, av0));
        float nv1 = fmaf(a10, Pv0, fmaf(a11, Pv1, av1));
        P00 = n00; P01 = n01; P10 = n10; P11 = n11; Pv0 = nv0; Pv1 = nv1;
    }
    // in-wave exclusive prefix E (identity at lane 0)
    float E00 = __shfl_up(L00, 1), E01 = __shfl_up(L01, 1);
    float E10 = __shfl_up(L10, 1), E11 = __shfl_up(L11, 1);
    float Ev0 = __shfl_up(Lv0, 1), Ev1 = __shfl_up(Lv1, 1);
    if (lane == 0) { E00 = 1.f; E01 = 0.f; E10 = 0.f; E11 = 1.f; Ev0 = 0.f; Ev1 = 0.f; }
    // start state (zero global init): s = E(P(0)) = M_E·v_P + v_E
    float s0 = fmaf(E00, Pv0, fmaf(E01, Pv1, Ev0));
    float s1 = fmaf(E10, Pv0, fmaf(E11, Pv1, Ev1));
    // replay: write each chunk's initial state, advance
    for (int j = 0; j < RPL; ++j) {
        int idx = base + j;
        init[idx] = s0;
        init[TCv + idx] = s1;
        float r00 = rec[0 * TCv + idx], r01 = rec[1 * TCv + idx];
        float r10 = rec[2 * TCv + idx], r11 = rec[3 * TCv + idx];
        float q0  = rec[4 * TCv + idx], q1  = rec[5 * TCv + idx];
        float ns0 = fmaf(r00, s0, fmaf(r01, s1, q0));
        float ns1 = fmaf(r10, s0, fmaf(r11, s1, q1));
        s0 = ns0; s1 = ns1;
    }
}

// ---- Kernel C: rerun chunks with correct init, fused FIR, LDS-coalesced writes ----
template<int CH>
__global__ __launch_bounds__(256) void k_apply(
    const float* __restrict__ x,
    const float* __restrict__ cl,
    const float* __restrict__ init,
    float* __restrict__ out)
{
    constexpr int NCv = NSAMP / CH;
    constexpr int TCv = BATCH * NCv;
    constexpr int LNC = ilog2c(NCv);
    constexpr int NP = CH / TSZ;
    __shared__ float sm[256][TSZ + 1];
    int tid = threadIdx.x;
    int chunk = blockIdx.x * 256 + tid;
    int r = chunk >> LNC;
    int c = chunk & (NCv - 1);
    const float scale = 255.0f / 262143.0f;
    int t0 = c * CH;
    float pos0 = (float)t0 * scale;
    float fiA = floorf(pos0);
    int idxA = (int)fiA;
    const float* kb = cl + (size_t)r * NKNOT * 5;
    int i0 = idxA;
    int i1 = min(idxA + 1, NKNOT - 1);
    int i2 = min(idxA + 2, NKNOT - 1);
    float k00 = kb[i0 * 5 + 0], k01 = kb[i1 * 5 + 0], k02 = kb[i2 * 5 + 0];
    float k10 = kb[i0 * 5 + 1], k11 = kb[i1 * 5 + 1], k12 = kb[i2 * 5 + 1];
    float k20 = kb[i0 * 5 + 2], k21 = kb[i1 * 5 + 2], k22 = kb[i2 * 5 + 2];
    float k30 = kb[i0 * 5 + 3], k31 = kb[i1 * 5 + 3], k32 = kb[i2 * 5 + 3];
    float k40 = kb[i0 * 5 + 4], k41 = kb[i1 * 5 + 4], k42 = kb[i2 * 5 + 4];

    const float* xp = x + (size_t)chunk * CH;
    size_t blockBase = (size_t)blockIdx.x * 256 * CH;
    float y1 = init[chunk];
    float y2 = init[TCv + chunk];
    const float stab = 1.0f - EPSV;
    const float stab2 = 2.0f * stab;

    for (int p = 0; p < NP; ++p) {
        for (int j = 0; j < TSZ; j += 4) {
            float4 xv = *(const float4*)(xp + p * TSZ + j);
            #pragma unroll
            for (int q = 0; q < 4; ++q) {
                int jj = p * TSZ + j + q;
                float xs = (&xv.x)[q];
                float wA = fmaf((float)jj, scale, pos0) - fiA;
                bool sel = wA >= 1.0f;
                float w = sel ? (wA - 1.0f) : wA;
                float l0a = sel ? k01 : k00, l0b = sel ? k02 : k01;
                float l1a = sel ? k11 : k10, l1b = sel ? k12 : k11;
                float b0a = sel ? k21 : k20, b0b = sel ? k22 : k21;
                float b1a = sel ? k31 : k30, b1b = sel ? k32 : k31;
                float b2a = sel ? k41 : k40, b2b = sel ? k42 : k41;
                float l0 = fmaf(w, l0b - l0a, l0a);
                float l1 = fmaf(w, l1b - l1a, l1a);
                float b0 = fmaf(w, b0b - b0a, b0a);
                float b1 = fmaf(w, b1b - b1a, b1a);
                float b2 = fmaf(w, b2b - b2a, b2a);
                float a1 = stab2 * fast_tanh(l0);
                float a1a = fabsf(a1);
                float a2 = 0.5f * fmaf((2.0f - a1a) * stab, fast_tanh(l1), a1a);
                float y = fmaf(-a2, y2, xs);  y = fmaf(-a1, y1, y);
                sm[tid][j + q] = fmaf(b0, y, fmaf(b1, y1, b2 * y2));
                y2 = y1; y1 = y;
            }
        }
        __syncthreads();
        // coalesced write: consecutive lanes -> consecutive addresses (full 64B lines)
        #pragma unroll
        for (int i = tid; i < 256 * TSZ; i += 256) {
            int cc = i >> 4;          // TSZ == 16
            int qq = i & 15;
            out[blockBase + (size_t)cc * CH + p * TSZ + qq] = sm[cc][qq];
        }
        __syncthreads();
    }
}

template<int CH>
static void run_all(const float* x, const float* cl, float* out,
                    void* d_ws, hipStream_t stream) {
    constexpr int NCv = NSAMP / CH;
    constexpr int TCv = BATCH * NCv;
    float* rec = (float*)d_ws;                 // 6*TCv floats
    float* init = rec + 6 * (size_t)TCv;       // 2*TCv floats
    hipLaunchKernelGGL(k_build<CH>, dim3(TCv / 256), dim3(256), 0, stream, x, cl, rec);
    hipLaunchKernelGGL(k_scan<CH>,  dim3(BATCH),     dim3(256), 0, stream, rec, init);
    hipLaunchKernelGGL(k_apply<CH>, dim3(TCv / 256), dim3(256), 0, stream, x, cl, init, out);
}

extern "C" void kernel_launch(void* const* d_in, const int* in_sizes, int n_in,
                              void* d_out, int out_size, void* d_ws, size_t ws_size,
                              hipStream_t stream) {
    const float* x  = (const float*)d_in[0];   // [32][262144]
    const float* cl = (const float*)d_in[1];   // [32][256][5]
    float* out = (float*)d_out;

    const size_t need32 = (size_t)8 * BATCH * (NSAMP / 32) * 4;   // ~8.4 MB
    const size_t need64 = (size_t)8 * BATCH * (NSAMP / 64) * 4;   // ~4.2 MB
    if (ws_size >= need32)      run_all<32>(x, cl, out, d_ws, stream);
    else if (ws_size >= need64) run_all<64>(x, cl, out, d_ws, stream);
    else                        run_all<128>(x, cl, out, d_ws, stream);
}